// Round 24
// baseline (130.547 us; speedup 1.0000x reference)
//
#include <hip/hip_runtime.h>
#include <hip/hip_bf16.h>
#include <math.h>

#pragma clang fp contract(off)

#define NRES 768
#define FIN 316
#define DPAIR 128
#define NCHUNK 9216   // 768*768/64 pairs per chunk of 64
#define NBLOCK 512
#define NTHREAD 512
#define NWAVES (NBLOCK * (NTHREAD/64))

typedef unsigned int u32;
typedef unsigned short u16;
typedef __attribute__((ext_vector_type(2))) float f32x2;
typedef __attribute__((ext_vector_type(4))) float f32x4;

#define PI64 3.141592653589793

// ---- compile-time f32 thresholds: t_k = smallest f32 with (double)t > lim_k ----
// For f32 v:  (lim_k < (double)v)  ⟺  (v >= t_k)   [exact; r16/r17-verified on HW]
constexpr float thr_up(double lim){
  float f = (float)lim;
  if ((double)f > lim) return f;
  unsigned b = __builtin_bit_cast(unsigned, f);
  b = (f > 0.0f) ? b + 1u : b - 1u;     // limits are never zero
  return __builtin_bit_cast(float, b);
}
struct Thr20 { float v[20]; };
constexpr Thr20 mkThr(double start, double step, double stop){
  Thr20 t{};
  for (int k = 0; k < 19; ++k) t.v[k] = thr_up((double)k * step + start);
  t.v[19] = thr_up(stop);
  return t;
}
constexpr double DSTEP = (2.0 - 0.1) / 19.0;
constexpr double ASTEP = (PI64 + PI64) / 19.0;
constexpr Thr20 TDIST = mkThr(0.1, DSTEP, 2.0);
constexpr Thr20 TANG  = mkThr(-PI64, ASTEP, PI64);

__device__ __forceinline__ u32 binIdx32(float v, const Thr20& T){
  u32 c = 0;
#pragma unroll
  for (int k = 0; k < 20; ++k) c += (v >= T.v[k]) ? 1u : 0u;
  return c;
}

struct V3 { float x, y, z; };

__device__ __forceinline__ V3 vsub(const V3 a, const V3 b){
  V3 r; r.x = a.x - b.x; r.y = a.y - b.y; r.z = a.z - b.z; return r;
}
__device__ __forceinline__ V3 vcross(const V3 a, const V3 b){
  V3 r;
  r.x = a.y*b.z - a.z*b.y;
  r.y = a.z*b.x - a.x*b.z;
  r.z = a.x*b.y - a.y*b.x;
  return r;
}
// init-0 reduce (verified): normalizes -0 sums to +0 (gold's diagonal behavior)
__device__ __forceinline__ float vdot(const V3 a, const V3 b){
  float s = 0.0f + a.x*b.x;
  s = s + a.y*b.y;
  s = s + a.z*b.z;
  return s;
}
__device__ __forceinline__ float sumsq3(float x, float y, float z){
  float s = 0.0f + x*x;
  s = s + y*y;
  s = s + z*z;
  return s;
}
// plain f32 div & sqrtf are correctly rounded under hipcc defaults (verified)
__device__ __forceinline__ V3 vnorm(const V3 v){
  float ss = sumsq3(v.x, v.y, v.z) + 1e-16f;
  float r = sqrtf(ss);
  float c = fmaxf(r, 1e-8f);
  V3 o; o.x = v.x / c; o.y = v.y / c; o.z = v.z / c; return o;
}

// angle bin (verified bit-exact): zero cases explicit; fast ocml atan2f with
// +-1.2e-6 double-count guard; rare (~5e-4) fallback to CR f64 atan2.
__device__ u32 angBin(float yy, float xx){
  if (yy == 0.0f) {
    float pi_f = __builtin_bit_cast(float, 0x40490fdbu);
    bool xneg = (__float_as_uint(xx) >> 31) != 0;
    float th = xneg ? ((__float_as_uint(yy) >> 31) ? -pi_f : pi_f) : yy;
    return binIdx32(th, TANG);
  }
  if (xx == 0.0f) {
    float p2 = __builtin_bit_cast(float, 0x3fc90fdbu);
    return binIdx32((yy > 0.0f) ? p2 : -p2, TANG);
  }
  float th = atan2f(yy, xx);                  // <=2 ulp (ocml)
  u32 cLo = binIdx32(th - 1.2e-6f, TANG);     // 1.2e-6 > 5 ulp @ |th|<=pi
  u32 cHi = binIdx32(th + 1.2e-6f, TANG);
  if (cLo == cHi) return cHi;                 // bin proven
  float tc = (float)atan2((double)yy, (double)xx);  // CR f32 (verified gold flavor)
  return binIdx32(tc, TANG);
}

__device__ u32 dihedBin(V3 a, V3 b, V3 c, V3 d){
  V3 v1 = vsub(b, a), v2 = vsub(c, b), v3 = vsub(d, c);
  V3 n1 = vnorm(vcross(v1, v2));
  V3 n2 = vnorm(vcross(v2, v3));
  V3 m  = vcross(n1, n2);
  float dt = vdot(m, v2);
  float sg = (dt > 0.0f) ? 1.0f : ((dt < 0.0f) ? -1.0f : dt);
  float ss = sumsq3(m.x, m.y, m.z) + 1e-16f;
  float yy = sg * sqrtf(ss);
  float xx = vdot(n1, n2);
  return angBin(yy, xx);
}

__device__ u32 bondBin(V3 a, V3 b, V3 c){
  V3 u = vnorm(vsub(b, a));
  V3 v = vnorm(vsub(c, a));
  V3 m = vcross(u, v);
  float ss = sumsq3(m.x, m.y, m.z) + 1e-16f;
  float yy = sqrtf(ss);
  float xx = vdot(u, v);
  return angBin(yy, xx);
}

// Quarter-wave DPP sum: after 4 row_shr stages, lane 15 of each 16-lane row
// holds the row sum (DPP row = 16 lanes on CDNA).
template<int CTRL, int RMASK>
__device__ __forceinline__ float dpp_add(float x){
  int v = __builtin_amdgcn_update_dpp(0, __float_as_int(x), CTRL, RMASK, 0xf, true);
  return x + __int_as_float(v);
}
__device__ __forceinline__ float quarterwave_sum(float x){
  x = dpp_add<0x111, 0xf>(x);
  x = dpp_add<0x112, 0xf>(x);
  x = dpp_add<0x114, 0xf>(x);
  x = dpp_add<0x118, 0xf>(x);
  return x;
}

// ---- kernel A: W[128][316] f32 -> Wt[316][128] bf16 (RNE) ----
__global__ void prep_kernel(const float* __restrict__ W, u16* __restrict__ Wt){
  int e = blockIdx.x * 256 + threadIdx.x;
  if (e < FIN * DPAIR) {
    int d = e / FIN;
    int f = e - d * FIN;
    u32 u = __float_as_uint(W[e]);
    u32 r = (u + 0x7fffu + ((u >> 16) & 1u)) >> 16;
    Wt[f * DPAIR + d] = (u16)r;
  }
}

__global__ __launch_bounds__(NTHREAD, 4) void pairfeat_kernel(
    const float* __restrict__ mask, const float* __restrict__ cmask,
    const float* __restrict__ cnm, const float* __restrict__ crd,
    const float* __restrict__ W, const u16* __restrict__ Wt, const int useWt,
    const float* __restrict__ bias, const float* __restrict__ gam,
    const float* __restrict__ bet, float* __restrict__ out)
{
  __shared__ u32 Wl[FIN * 64];   // [f][d-pair] bf16 pairs packed as u32: 80,896 B

  if (useWt) {
    const u32* src = (const u32*)Wt;
    for (int e = threadIdx.x; e < FIN * 64; e += NTHREAD) Wl[e] = src[e];
  } else {
    for (int e = threadIdx.x; e < FIN * DPAIR; e += NTHREAD) {
      int d = e & 127, f = e >> 7;
      u32 u = __float_as_uint(W[d * FIN + f]);
      u32 r = (u + 0x7fffu + ((u >> 16) & 1u)) >> 16;
      ((u16*)Wl)[f * DPAIR + d] = (u16)r;
    }
  }
  __syncthreads();

  const int lane = threadIdx.x & 63;
  const int gw = (blockIdx.x * NTHREAD + threadIdx.x) >> 6;
  const int l4 = lane & 15;          // dim-group index within quarter-wave
  const int g  = (lane >> 4) & 3;    // which of 4 pairs this lane serves
  const int dbase = l4 * 8;          // this lane's 8 dims
  const float4 bv0 = *(const float4*)(bias + dbase);
  const float4 bv1 = *(const float4*)(bias + dbase + 4);
  const float4 gv0 = *(const float4*)(gam + dbase);
  const float4 gv1 = *(const float4*)(gam + dbase + 4);
  const float4 ev0 = *(const float4*)(bet + dbase);
  const float4 ev1 = *(const float4*)(bet + dbase + 4);

  for (int ch = gw; ch < NCHUNK; ch += NWAVES) {
    const int i = ch / 12;
    const int j = (ch - i * 12) * 64 + lane;

    // ----- phase 1: per-lane pair (i, j) bins + weights (verified bit-exact) -----
    float mi = mask[i], mj = mask[j];
    float hci = cmask[i * 4 + 3], hcj = cmask[j * 4 + 3];
    float pm = mi * mj;

    const float4* jq = (const float4*)(cnm + (size_t)j * 12);
    float4 q0 = jq[0], q1 = jq[1], q2 = jq[2];
    float cax = cnm[i*12+3], cay = cnm[i*12+4], caz = cnm[i*12+5];

    int sepb = i - j + 63;
    sepb = sepb < 0 ? 0 : (sepb > 126 ? 126 : sepb);
    u32 pack0 = (u32)sepb;
    {
      float ax[4] = {q0.x, q0.w, q1.z, q2.y};
      float ay[4] = {q0.y, q1.x, q1.w, q2.z};
      float az[4] = {q0.z, q1.y, q2.x, q2.w};
      int sh = 7;
#pragma unroll
      for (int a = 0; a < 4; ++a) {
        float dx = cax - ax[a];
        float dy = cay - ay[a];
        float dz = caz - az[a];
        float ss = sumsq3(dx, dy, dz) + 1e-10f;
        float dist = sqrtf(ss);                       // CR
        pack0 |= binIdx32(dist, TDIST) << sh; sh += 5;
      }
    }

    const float4* jr = (const float4*)(crd + (size_t)j * 12);
    float4 r0 = jr[0], r1 = jr[1], r2 = jr[2];
    V3 Nj  = {r0.x, r0.y, r0.z};
    V3 CAj = {r0.w, r1.x, r1.y};
    V3 CBj = {r2.y, r2.z, r2.w};
    V3 Ni  = {crd[i*12+0], crd[i*12+1], crd[i*12+2]};
    V3 CAi = {crd[i*12+3], crd[i*12+4], crd[i*12+5]};
    V3 CBi = {crd[i*12+9], crd[i*12+10], crd[i*12+11]};

    u32 pack1 = 0;
    pack1 |= dihedBin(Ni, CAi, CBi, CBj);
    pack1 |= dihedBin(Nj, CAj, CBj, CBi) << 5;
    pack1 |= bondBin(CAi, CBi, CBj) << 10;
    pack1 |= bondBin(CAj, CBj, CBi) << 15;
    pack1 |= dihedBin(CAi, CBi, CBj, CAj) << 20;

    float pm2 = pm * pm;
    float wbb = pm2;
    float wbb3 = pm2 * hcj;
    float tw = pm * hci; tw = tw * hci; float wor = tw * pm;

    // ----- phase 2: 4 pairs/iter; quarter-wave (16 lanes, 8 dims/lane) per pair -----
    float* ob = out + (size_t)ch * (64 * DPAIR);
#pragma unroll 4
    for (int p = 0; p < 64; p += 4) {
      const int pidx = p + g;
      u32 k0 = (u32)__shfl((int)pack0, pidx);   // ds_bpermute: per-lane source
      u32 k1 = (u32)__shfl((int)pack1, pidx);
      float Pm  = __shfl(pm, pidx);
      float Wbb = __shfl(wbb, pidx);
      float Wb3 = __shfl(wbb3, pidx);
      float Wor = __shfl(wor, pidx);

      u32 cidx[10];
      cidx[0] = (k0 & 127u);
      cidx[1] = 127u +        ((k0 >> 7)  & 31u);
      cidx[2] = 127u + 21u +  ((k0 >> 12) & 31u);
      cidx[3] = 127u + 42u +  ((k0 >> 17) & 31u);
      cidx[4] = 127u + 63u +  ((k0 >> 22) & 31u);
      cidx[5] = 211u +        (k1 & 31u);
      cidx[6] = 211u + 21u +  ((k1 >> 5)  & 31u);
      cidx[7] = 211u + 42u +  ((k1 >> 10) & 31u);
      cidx[8] = 211u + 63u +  ((k1 >> 15) & 31u);
      cidx[9] = 211u + 84u +  ((k1 >> 20) & 31u);
      float wv[10] = {Pm, Wbb, Wbb, Wbb, Wb3, Wor, Wor, Wor, Wor, Wor};

      f32x2 a01 = {bv0.x, bv0.y}, a23 = {bv0.z, bv0.w};
      f32x2 a45 = {bv1.x, bv1.y}, a67 = {bv1.z, bv1.w};
      float s, s2;
      {
#pragma clang fp contract(fast)
#pragma unroll
        for (int t = 0; t < 10; ++t) {
          uint4 u4 = *(const uint4*)&Wl[cidx[t] * 64 + l4 * 4];  // dims 8*l4..+7
          f32x2 w01, w23, w45, w67;
          w01.x = __uint_as_float(u4.x << 16);
          w01.y = __uint_as_float(u4.x & 0xffff0000u);
          w23.x = __uint_as_float(u4.y << 16);
          w23.y = __uint_as_float(u4.y & 0xffff0000u);
          w45.x = __uint_as_float(u4.z << 16);
          w45.y = __uint_as_float(u4.z & 0xffff0000u);
          w67.x = __uint_as_float(u4.w << 16);
          w67.y = __uint_as_float(u4.w & 0xffff0000u);
          f32x2 wt = {wv[t], wv[t]};
          a01 = a01 + wt * w01;     // -> v_pk_fma_f32
          a23 = a23 + wt * w23;
          a45 = a45 + wt * w45;
          a67 = a67 + wt * w67;
        }
        f32x2 t1 = a01 + a23, t2 = a45 + a67;
        f32x2 t3 = t1 + t2;
        s = t3.x + t3.y;
        f32x2 q = a01 * a01 + a23 * a23 + a45 * a45 + a67 * a67;
        s2 = q.x + q.y;
      }
      s  = quarterwave_sum(s);
      s2 = quarterwave_sum(s2);
      float sB  = __shfl(s,  lane | 15);   // broadcast row sum within 16-lane row
      float s2B = __shfl(s2, lane | 15);
      float mu = sB * 0.0078125f;
      float var = fmaf(s2B, 0.0078125f, -(mu * mu));
      float inv = __builtin_amdgcn_rsqf(var + 1e-5f);
      f32x2 mu2 = {mu, mu}, inv2 = {inv, inv}, Pm2 = {Pm, Pm};
      f32x2 o01, o23, o45, o67;
      {
#pragma clang fp contract(fast)
        f32x2 g01 = {gv0.x, gv0.y}, g23 = {gv0.z, gv0.w};
        f32x2 g45 = {gv1.x, gv1.y}, g67 = {gv1.z, gv1.w};
        f32x2 e01 = {ev0.x, ev0.y}, e23 = {ev0.z, ev0.w};
        f32x2 e45 = {ev1.x, ev1.y}, e67 = {ev1.z, ev1.w};
        o01 = ((a01 - mu2) * inv2 * g01 + e01) * Pm2;
        o23 = ((a23 - mu2) * inv2 * g23 + e23) * Pm2;
        o45 = ((a45 - mu2) * inv2 * g45 + e45) * Pm2;
        o67 = ((a67 - mu2) * inv2 * g67 + e67) * Pm2;
      }
      float* orow = ob + (size_t)pidx * DPAIR + dbase;
      f32x4 ov0 = {o01.x, o01.y, o23.x, o23.y};
      f32x4 ov1 = {o45.x, o45.y, o67.x, o67.y};
      __builtin_nontemporal_store(ov0, (f32x4*)(orow));
      __builtin_nontemporal_store(ov1, (f32x4*)(orow + 4));
    }
  }
}

extern "C" void kernel_launch(void* const* d_in, const int* in_sizes, int n_in,
                              void* d_out, int out_size, void* d_ws, size_t ws_size,
                              hipStream_t stream) {
  const float* mask  = (const float*)d_in[0];
  const float* cmask = (const float*)d_in[1];
  const float* cnm   = (const float*)d_in[2];
  const float* crd   = (const float*)d_in[3];
  const float* W     = (const float*)d_in[4];
  const float* bias  = (const float*)d_in[5];
  const float* gam   = (const float*)d_in[6];
  const float* bet   = (const float*)d_in[7];
  float* out = (float*)d_out;

  const size_t wtBytes = (size_t)FIN * DPAIR * sizeof(u16);
  int useWt = (ws_size >= wtBytes) ? 1 : 0;
  u16* Wt = (u16*)d_ws;
  if (useWt) {
    prep_kernel<<<(FIN * DPAIR + 255) / 256, 256, 0, stream>>>(W, Wt);
  }
  pairfeat_kernel<<<NBLOCK, NTHREAD, 0, stream>>>(
      mask, cmask, cnm, crd, W, Wt, useWt, bias, gam, bet, out);
}

// Round 25
// 107.177 us; speedup vs baseline: 1.2181x; 1.2181x over previous
//
#include <hip/hip_runtime.h>
#include <hip/hip_bf16.h>
#include <math.h>

#pragma clang fp contract(off)

#define NRES 768
#define FIN 316
#define DPAIR 128
#define NCHUNK 9216   // 768*768/64 pairs per chunk of 64
#define NBLOCK 512
#define NTHREAD 512
#define NWAVES (NBLOCK * (NTHREAD/64))

typedef unsigned int u32;
typedef unsigned short u16;
typedef __attribute__((ext_vector_type(2))) float f32x2;

#define PI64 3.141592653589793

// ---- compile-time f32 thresholds: t_k = smallest f32 with (double)t > lim_k ----
// For f32 v:  (lim_k < (double)v)  ⟺  (v >= t_k)   [exact; r16/r17-verified on HW]
constexpr float thr_up(double lim){
  float f = (float)lim;
  if ((double)f > lim) return f;
  unsigned b = __builtin_bit_cast(unsigned, f);
  b = (f > 0.0f) ? b + 1u : b - 1u;     // limits are never zero
  return __builtin_bit_cast(float, b);
}
struct Thr20 { float v[20]; };
constexpr Thr20 mkThr(double start, double step, double stop){
  Thr20 t{};
  for (int k = 0; k < 19; ++k) t.v[k] = thr_up((double)k * step + start);
  t.v[19] = thr_up(stop);
  return t;
}
constexpr double DSTEP = (2.0 - 0.1) / 19.0;
constexpr double ASTEP = (PI64 + PI64) / 19.0;
constexpr Thr20 TDIST = mkThr(0.1, DSTEP, 2.0);
constexpr Thr20 TANG  = mkThr(-PI64, ASTEP, PI64);

__device__ __forceinline__ u32 binIdx32(float v, const Thr20& T){
  u32 c = 0;
#pragma unroll
  for (int k = 0; k < 20; ++k) c += (v >= T.v[k]) ? 1u : 0u;
  return c;
}

struct V3 { float x, y, z; };

__device__ __forceinline__ V3 vsub(const V3 a, const V3 b){
  V3 r; r.x = a.x - b.x; r.y = a.y - b.y; r.z = a.z - b.z; return r;
}
__device__ __forceinline__ V3 vcross(const V3 a, const V3 b){
  V3 r;
  r.x = a.y*b.z - a.z*b.y;
  r.y = a.z*b.x - a.x*b.z;
  r.z = a.x*b.y - a.y*b.x;
  return r;
}
// init-0 reduce (verified): normalizes -0 sums to +0 (gold's diagonal behavior)
__device__ __forceinline__ float vdot(const V3 a, const V3 b){
  float s = 0.0f + a.x*b.x;
  s = s + a.y*b.y;
  s = s + a.z*b.z;
  return s;
}
__device__ __forceinline__ float sumsq3(float x, float y, float z){
  float s = 0.0f + x*x;
  s = s + y*y;
  s = s + z*z;
  return s;
}
// plain f32 div & sqrtf are correctly rounded under hipcc defaults (verified)
__device__ __forceinline__ V3 vnorm(const V3 v){
  float ss = sumsq3(v.x, v.y, v.z) + 1e-16f;
  float r = sqrtf(ss);
  float c = fmaxf(r, 1e-8f);
  V3 o; o.x = v.x / c; o.y = v.y / c; o.z = v.z / c; return o;
}

// angle bin (verified bit-exact): zero cases explicit; fast ocml atan2f with
// +-1.2e-6 double-count guard; rare (~5e-4) fallback to CR f64 atan2.
__device__ u32 angBin(float yy, float xx){
  if (yy == 0.0f) {
    float pi_f = __builtin_bit_cast(float, 0x40490fdbu);
    bool xneg = (__float_as_uint(xx) >> 31) != 0;
    float th = xneg ? ((__float_as_uint(yy) >> 31) ? -pi_f : pi_f) : yy;
    return binIdx32(th, TANG);
  }
  if (xx == 0.0f) {
    float p2 = __builtin_bit_cast(float, 0x3fc90fdbu);
    return binIdx32((yy > 0.0f) ? p2 : -p2, TANG);
  }
  float th = atan2f(yy, xx);                  // <=2 ulp (ocml)
  u32 cLo = binIdx32(th - 1.2e-6f, TANG);     // 1.2e-6 > 5 ulp @ |th|<=pi
  u32 cHi = binIdx32(th + 1.2e-6f, TANG);
  if (cLo == cHi) return cHi;                 // bin proven
  float tc = (float)atan2((double)yy, (double)xx);  // CR f32 (verified gold flavor)
  return binIdx32(tc, TANG);
}

__device__ u32 dihedBin(V3 a, V3 b, V3 c, V3 d){
  V3 v1 = vsub(b, a), v2 = vsub(c, b), v3 = vsub(d, c);
  V3 n1 = vnorm(vcross(v1, v2));
  V3 n2 = vnorm(vcross(v2, v3));
  V3 m  = vcross(n1, n2);
  float dt = vdot(m, v2);
  float sg = (dt > 0.0f) ? 1.0f : ((dt < 0.0f) ? -1.0f : dt);
  float ss = sumsq3(m.x, m.y, m.z) + 1e-16f;
  float yy = sg * sqrtf(ss);
  float xx = vdot(n1, n2);
  return angBin(yy, xx);
}

__device__ u32 bondBin(V3 a, V3 b, V3 c){
  V3 u = vnorm(vsub(b, a));
  V3 v = vnorm(vsub(c, a));
  V3 m = vcross(u, v);
  float ss = sumsq3(m.x, m.y, m.z) + 1e-16f;
  float yy = sqrtf(ss);
  float xx = vdot(u, v);
  return angBin(yy, xx);
}

// Quarter-wave DPP sum: after 4 row_shr stages, lane 15 of each 16-lane row
// holds the row sum (DPP row = 16 lanes on CDNA).
template<int CTRL, int RMASK>
__device__ __forceinline__ float dpp_add(float x){
  int v = __builtin_amdgcn_update_dpp(0, __float_as_int(x), CTRL, RMASK, 0xf, true);
  return x + __int_as_float(v);
}
__device__ __forceinline__ float quarterwave_sum(float x){
  x = dpp_add<0x111, 0xf>(x);
  x = dpp_add<0x112, 0xf>(x);
  x = dpp_add<0x114, 0xf>(x);
  x = dpp_add<0x118, 0xf>(x);
  return x;
}

// ---- kernel A: W[128][316] f32 -> Wt[316][128] bf16 (RNE) ----
__global__ void prep_kernel(const float* __restrict__ W, u16* __restrict__ Wt){
  int e = blockIdx.x * 256 + threadIdx.x;
  if (e < FIN * DPAIR) {
    int d = e / FIN;
    int f = e - d * FIN;
    u32 u = __float_as_uint(W[e]);
    u32 r = (u + 0x7fffu + ((u >> 16) & 1u)) >> 16;
    Wt[f * DPAIR + d] = (u16)r;
  }
}

__global__ __launch_bounds__(NTHREAD, 4) void pairfeat_kernel(
    const float* __restrict__ mask, const float* __restrict__ cmask,
    const float* __restrict__ cnm, const float* __restrict__ crd,
    const float* __restrict__ W, const u16* __restrict__ Wt, const int useWt,
    const float* __restrict__ bias, const float* __restrict__ gam,
    const float* __restrict__ bet, float* __restrict__ out)
{
  __shared__ u32 Wl[FIN * 64];   // [f][d-pair] bf16 pairs packed as u32: 80,896 B

  if (useWt) {
    const u32* src = (const u32*)Wt;
    for (int e = threadIdx.x; e < FIN * 64; e += NTHREAD) Wl[e] = src[e];
  } else {
    for (int e = threadIdx.x; e < FIN * DPAIR; e += NTHREAD) {
      int d = e & 127, f = e >> 7;
      u32 u = __float_as_uint(W[d * FIN + f]);
      u32 r = (u + 0x7fffu + ((u >> 16) & 1u)) >> 16;
      ((u16*)Wl)[f * DPAIR + d] = (u16)r;
    }
  }
  __syncthreads();

  const int lane = threadIdx.x & 63;
  const int gw = (blockIdx.x * NTHREAD + threadIdx.x) >> 6;
  const int l4 = lane & 15;          // dim-group index within quarter-wave
  const int g  = (lane >> 4) & 3;    // which of 4 pairs this lane serves
  const int dbase = l4 * 8;          // this lane's 8 dims
  const float4 bv0 = *(const float4*)(bias + dbase);
  const float4 bv1 = *(const float4*)(bias + dbase + 4);
  const float4 gv0 = *(const float4*)(gam + dbase);
  const float4 gv1 = *(const float4*)(gam + dbase + 4);
  const float4 ev0 = *(const float4*)(bet + dbase);
  const float4 ev1 = *(const float4*)(bet + dbase + 4);

  for (int ch = gw; ch < NCHUNK; ch += NWAVES) {
    const int i = ch / 12;
    const int j = (ch - i * 12) * 64 + lane;

    // ----- phase 1: per-lane pair (i, j) bins + weights (verified bit-exact) -----
    float mi = mask[i], mj = mask[j];
    float hci = cmask[i * 4 + 3], hcj = cmask[j * 4 + 3];
    float pm = mi * mj;

    const float4* jq = (const float4*)(cnm + (size_t)j * 12);
    float4 q0 = jq[0], q1 = jq[1], q2 = jq[2];
    float cax = cnm[i*12+3], cay = cnm[i*12+4], caz = cnm[i*12+5];

    int sepb = i - j + 63;
    sepb = sepb < 0 ? 0 : (sepb > 126 ? 126 : sepb);
    u32 pack0 = (u32)sepb;
    {
      float ax[4] = {q0.x, q0.w, q1.z, q2.y};
      float ay[4] = {q0.y, q1.x, q1.w, q2.z};
      float az[4] = {q0.z, q1.y, q2.x, q2.w};
      int sh = 7;
#pragma unroll
      for (int a = 0; a < 4; ++a) {
        float dx = cax - ax[a];
        float dy = cay - ay[a];
        float dz = caz - az[a];
        float ss = sumsq3(dx, dy, dz) + 1e-10f;
        float dist = sqrtf(ss);                       // CR
        pack0 |= binIdx32(dist, TDIST) << sh; sh += 5;
      }
    }

    const float4* jr = (const float4*)(crd + (size_t)j * 12);
    float4 r0 = jr[0], r1 = jr[1], r2 = jr[2];
    V3 Nj  = {r0.x, r0.y, r0.z};
    V3 CAj = {r0.w, r1.x, r1.y};
    V3 CBj = {r2.y, r2.z, r2.w};
    V3 Ni  = {crd[i*12+0], crd[i*12+1], crd[i*12+2]};
    V3 CAi = {crd[i*12+3], crd[i*12+4], crd[i*12+5]};
    V3 CBi = {crd[i*12+9], crd[i*12+10], crd[i*12+11]};

    u32 pack1 = 0;
    pack1 |= dihedBin(Ni, CAi, CBi, CBj);
    pack1 |= dihedBin(Nj, CAj, CBj, CBi) << 5;
    pack1 |= bondBin(CAi, CBi, CBj) << 10;
    pack1 |= bondBin(CAj, CBj, CBi) << 15;
    pack1 |= dihedBin(CAi, CBi, CBj, CAj) << 20;

    float pm2 = pm * pm;
    float wbb = pm2;
    float wbb3 = pm2 * hcj;
    float tw = pm * hci; tw = tw * hci; float wor = tw * pm;

    // ----- phase 2: 4 pairs/iter; quarter-wave (16 lanes, 8 dims/lane) per pair -----
    float* ob = out + (size_t)ch * (64 * DPAIR);
#pragma unroll 2
    for (int p = 0; p < 64; p += 4) {
      const int pidx = p + g;
      u32 k0 = (u32)__shfl((int)pack0, pidx);   // ds_bpermute: per-lane source
      u32 k1 = (u32)__shfl((int)pack1, pidx);
      float Pm  = __shfl(pm, pidx);
      float Wbb = __shfl(wbb, pidx);
      float Wb3 = __shfl(wbb3, pidx);
      float Wor = __shfl(wor, pidx);

      u32 cidx[10];
      cidx[0] = (k0 & 127u);
      cidx[1] = 127u +        ((k0 >> 7)  & 31u);
      cidx[2] = 127u + 21u +  ((k0 >> 12) & 31u);
      cidx[3] = 127u + 42u +  ((k0 >> 17) & 31u);
      cidx[4] = 127u + 63u +  ((k0 >> 22) & 31u);
      cidx[5] = 211u +        (k1 & 31u);
      cidx[6] = 211u + 21u +  ((k1 >> 5)  & 31u);
      cidx[7] = 211u + 42u +  ((k1 >> 10) & 31u);
      cidx[8] = 211u + 63u +  ((k1 >> 15) & 31u);
      cidx[9] = 211u + 84u +  ((k1 >> 20) & 31u);
      float wv[10] = {Pm, Wbb, Wbb, Wbb, Wb3, Wor, Wor, Wor, Wor, Wor};

      f32x2 a01 = {bv0.x, bv0.y}, a23 = {bv0.z, bv0.w};
      f32x2 a45 = {bv1.x, bv1.y}, a67 = {bv1.z, bv1.w};
      float s, s2;
      {
#pragma clang fp contract(fast)
#pragma unroll
        for (int t = 0; t < 10; ++t) {
          uint4 u4 = *(const uint4*)&Wl[cidx[t] * 64 + l4 * 4];  // dims 8*l4..+7
          f32x2 w01, w23, w45, w67;
          w01.x = __uint_as_float(u4.x << 16);
          w01.y = __uint_as_float(u4.x & 0xffff0000u);
          w23.x = __uint_as_float(u4.y << 16);
          w23.y = __uint_as_float(u4.y & 0xffff0000u);
          w45.x = __uint_as_float(u4.z << 16);
          w45.y = __uint_as_float(u4.z & 0xffff0000u);
          w67.x = __uint_as_float(u4.w << 16);
          w67.y = __uint_as_float(u4.w & 0xffff0000u);
          f32x2 wt = {wv[t], wv[t]};
          a01 = a01 + wt * w01;     // -> v_pk_fma_f32
          a23 = a23 + wt * w23;
          a45 = a45 + wt * w45;
          a67 = a67 + wt * w67;
        }
        f32x2 t1 = a01 + a23, t2 = a45 + a67;
        f32x2 t3 = t1 + t2;
        s = t3.x + t3.y;
        f32x2 q = a01 * a01 + a23 * a23 + a45 * a45 + a67 * a67;
        s2 = q.x + q.y;
      }
      s  = quarterwave_sum(s);
      s2 = quarterwave_sum(s2);
      float sB  = __shfl(s,  lane | 15);   // broadcast row sum within 16-lane row
      float s2B = __shfl(s2, lane | 15);
      float mu = sB * 0.0078125f;
      float var = fmaf(s2B, 0.0078125f, -(mu * mu));
      float inv = __builtin_amdgcn_rsqf(var + 1e-5f);
      f32x2 mu2 = {mu, mu}, inv2 = {inv, inv}, Pm2 = {Pm, Pm};
      f32x2 o01, o23, o45, o67;
      {
#pragma clang fp contract(fast)
        f32x2 g01 = {gv0.x, gv0.y}, g23 = {gv0.z, gv0.w};
        f32x2 g45 = {gv1.x, gv1.y}, g67 = {gv1.z, gv1.w};
        f32x2 e01 = {ev0.x, ev0.y}, e23 = {ev0.z, ev0.w};
        f32x2 e45 = {ev1.x, ev1.y}, e67 = {ev1.z, ev1.w};
        o01 = ((a01 - mu2) * inv2 * g01 + e01) * Pm2;
        o23 = ((a23 - mu2) * inv2 * g23 + e23) * Pm2;
        o45 = ((a45 - mu2) * inv2 * g45 + e45) * Pm2;
        o67 = ((a67 - mu2) * inv2 * g67 + e67) * Pm2;
      }
      float* orow = ob + (size_t)pidx * DPAIR + dbase;
      float4 ov0; ov0.x = o01.x; ov0.y = o01.y; ov0.z = o23.x; ov0.w = o23.y;
      float4 ov1; ov1.x = o45.x; ov1.y = o45.y; ov1.z = o67.x; ov1.w = o67.y;
      *(float4*)(orow)     = ov0;
      *(float4*)(orow + 4) = ov1;
    }
  }
}

extern "C" void kernel_launch(void* const* d_in, const int* in_sizes, int n_in,
                              void* d_out, int out_size, void* d_ws, size_t ws_size,
                              hipStream_t stream) {
  const float* mask  = (const float*)d_in[0];
  const float* cmask = (const float*)d_in[1];
  const float* cnm   = (const float*)d_in[2];
  const float* crd   = (const float*)d_in[3];
  const float* W     = (const float*)d_in[4];
  const float* bias  = (const float*)d_in[5];
  const float* gam   = (const float*)d_in[6];
  const float* bet   = (const float*)d_in[7];
  float* out = (float*)d_out;

  const size_t wtBytes = (size_t)FIN * DPAIR * sizeof(u16);
  int useWt = (ws_size >= wtBytes) ? 1 : 0;
  u16* Wt = (u16*)d_ws;
  if (useWt) {
    prep_kernel<<<(FIN * DPAIR + 255) / 256, 256, 0, stream>>>(W, Wt);
  }
  pairfeat_kernel<<<NBLOCK, NTHREAD, 0, stream>>>(
      mask, cmask, cnm, crd, W, Wt, useWt, bias, gam, bet, out);
}